// Round 2
// baseline (1416.758 us; speedup 1.0000x reference)
//
#include <hip/hip_runtime.h>
#include <hip/hip_bf16.h>

// Problem constants (B=2, T=2048 -> BT=4096 tokens)
#define CC   128
#define EE   16
#define KBB  32
#define VV   50257
#define BT   4096

typedef __bf16 bf16x8 __attribute__((ext_vector_type(8)));
typedef float  f32x4  __attribute__((ext_vector_type(4)));

__device__ inline unsigned short f2b(float f) {
    unsigned int i = __builtin_bit_cast(unsigned int, f);
    unsigned int r = (i + 0x7fffu + ((i >> 16) & 1u)) >> 16;   // RNE
    return (unsigned short)r;
}

// dot of a global f32 row (length 128, 16B-aligned) with an LDS f32 vector
__device__ inline float dotf(const float* __restrict__ p,
                             const float* __restrict__ sx) {
    float acc = 0.f;
#pragma unroll
    for (int c = 0; c < CC; c += 4) {
        const float4 a = *reinterpret_cast<const float4*>(p + c);
        const float4 b = *reinterpret_cast<const float4*>(sx + c);
        acc += a.x * b.x + a.y * b.y + a.z * b.z + a.w * b.w;
    }
    return acc;
}

__device__ inline float wsum(float v) {
#pragma unroll
    for (int m = 1; m < 64; m <<= 1) v += __shfl_xor(v, m, 64);
    return v;
}

__device__ inline float bsum128(float v, float* s_red) {
    v = wsum(v);
    __syncthreads();                    // protect s_red from previous use (WAR)
    if ((threadIdx.x & 63) == 0) s_red[threadIdx.x >> 6] = v;
    __syncthreads();
    return s_red[0] + s_red[1];
}

// One block (128 threads) per token: embed -> LN1 -> router softmax -> q ->
// expert-mixed KV attention -> Wo -> resid -> LN2 -> Wmlp -> resid.
// Emits gate_logits (f32, d_out tail) and x_final (bf16, to ws).
__global__ __launch_bounds__(128)
void token_kernel(const int* __restrict__ ids,
                  const float* __restrict__ emb,
                  const float* __restrict__ router,
                  const float* __restrict__ k_ex,
                  const float* __restrict__ v_ex,
                  const float* __restrict__ st_k,
                  const float* __restrict__ st_v,
                  const float* __restrict__ kv_gate,
                  const float* __restrict__ Wq,
                  const float* __restrict__ Wo,
                  const float* __restrict__ Wmlp,
                  const float* __restrict__ bmlp,
                  const float* __restrict__ g1,
                  const float* __restrict__ b1,
                  const float* __restrict__ g2,
                  const float* __restrict__ b2v,
                  float* __restrict__ gate_out,
                  unsigned short* __restrict__ xf_out)
{
    __shared__ __align__(16) float s_xln[CC];
    __shared__ __align__(16) float s_q[CC];
    __shared__ __align__(16) float s_m[EE * KBB];
    __shared__ __align__(16) float s_w[EE * KBB];
    __shared__ __align__(16) float s_pa[2 * CC];
    __shared__ __align__(16) float s_ao[CC];
    __shared__ __align__(16) float s_y[CC];
    __shared__ float s_ge[EE], s_rw[EE], s_sc[KBB], s_at[KBB], s_red[2];

    const int tid = threadIdx.x;
    const int t = blockIdx.x;

    const int id = ids[t];
    const float x0 = emb[(size_t)id * CC + tid];

    // ---- LN1 ----
    const float mu = bsum128(x0, s_red) * (1.f / CC);
    const float dx = x0 - mu;
    const float var = bsum128(dx * dx, s_red) * (1.f / CC);
    const float xln = dx * rsqrtf(var + 1e-5f) * g1[tid] + b1[tid];
    s_xln[tid] = xln;
    __syncthreads();

    // ---- gate logits + router softmax ----
    if (tid < EE) {
        const float acc = dotf(router + tid * CC, s_xln);
        s_ge[tid] = acc;
        gate_out[(size_t)t * EE + tid] = acc;
    }
    __syncthreads();
    float gm = s_ge[0];
#pragma unroll
    for (int e = 1; e < EE; e++) gm = fmaxf(gm, s_ge[e]);
    float gs = 0.f;
#pragma unroll
    for (int e = 0; e < EE; e++) gs += expf(s_ge[e] - gm);
    if (tid < EE) s_rw[tid] = expf(s_ge[tid] - gm) / gs;
    const float gg = 1.f / (1.f + expf(-kv_gate[0]));

    // ---- q = x_ln @ Wq^T ----
    s_q[tid] = dotf(Wq + tid * CC, s_xln);
    __syncthreads();

    // ---- m[e,k] = q . k_experts[e,k,:] ----
    for (int r = tid; r < EE * KBB; r += 128)
        s_m[r] = dotf(k_ex + (size_t)r * CC, s_q);
    __syncthreads();

    // ---- scores + softmax over KB ----
    if (tid < KBB) {
        float accs = 0.f;
#pragma unroll
        for (int e = 0; e < EE; e++) accs += s_rw[e] * s_m[e * KBB + tid];
        const float accst = dotf(st_k + tid * CC, s_q);
        s_sc[tid] = (gg * accs + (1.f - gg) * accst) * 0.08838834764831845f; // 1/sqrt(128)
    }
    __syncthreads();
    float am = s_sc[0];
#pragma unroll
    for (int k = 1; k < KBB; k++) am = fmaxf(am, s_sc[k]);
    float as = 0.f;
#pragma unroll
    for (int k = 0; k < KBB; k++) as += expf(s_sc[k] - am);
    if (tid < KBB) s_at[tid] = expf(s_sc[tid] - am) / as;
    __syncthreads();

    // ---- w[e,k] = rw[e]*attn[k] ----
    for (int r = tid; r < EE * KBB; r += 128) s_w[r] = s_rw[r >> 5] * s_at[r & 31];
    __syncthreads();

    // ---- dynamic V mix: each half-block covers 256 of 512 (e,k) rows, 2 channels/thread ----
    {
        const int h = tid >> 6;            // 0 or 1
        const int c0 = (tid & 63) * 2;
        const int rbase = h * 256;
        float a0 = 0.f, a1 = 0.f;
#pragma unroll 4
        for (int r = 0; r < 256; r++) {
            const float2 u =
                *reinterpret_cast<const float2*>(v_ex + (size_t)(rbase + r) * CC + c0);
            const float wgt = s_w[rbase + r];
            a0 += wgt * u.x;
            a1 += wgt * u.y;
        }
        s_pa[h * CC + c0] = a0;
        s_pa[h * CC + c0 + 1] = a1;
    }
    __syncthreads();

    // ---- static V + combine ----
    {
        float stat = 0.f;
#pragma unroll
        for (int k = 0; k < KBB; k++) stat += s_at[k] * st_v[k * CC + tid];
        s_ao[tid] = gg * (s_pa[tid] + s_pa[CC + tid]) + (1.f - gg) * stat;
    }
    __syncthreads();

    // ---- Wo projection + residual ----
    const float xr = x0 + dotf(Wo + tid * CC, s_ao);

    // ---- LN2 ----
    const float mu2 = bsum128(xr, s_red) * (1.f / CC);
    const float dx2 = xr - mu2;
    const float var2 = bsum128(dx2 * dx2, s_red) * (1.f / CC);
    s_y[tid] = dx2 * rsqrtf(var2 + 1e-5f) * g2[tid] + b2v[tid];
    __syncthreads();

    // ---- MLP + residual -> x_final (bf16 for MFMA) ----
    const float xf = xr + dotf(Wmlp + tid * CC, s_y) + bmlp[tid];
    xf_out[(size_t)t * CC + tid] = f2b(xf);
}

// Wlm f32 -> bf16 (RNE), 8 elems/thread
__global__ __launch_bounds__(256)
void convert_kernel(const float* __restrict__ src,
                    unsigned short* __restrict__ dst, int n8)
{
    const int i = blockIdx.x * 256 + threadIdx.x;
    if (i >= n8) return;
    const float4 a = *reinterpret_cast<const float4*>(src + (size_t)i * 8);
    const float4 b = *reinterpret_cast<const float4*>(src + (size_t)i * 8 + 4);
    unsigned short v[8] = {f2b(a.x), f2b(a.y), f2b(a.z), f2b(a.w),
                           f2b(b.x), f2b(b.y), f2b(b.z), f2b(b.w)};
    *reinterpret_cast<uint4*>(dst + (size_t)i * 8) = *reinterpret_cast<uint4*>(v);
}

// logits = x_final @ Wlm^T via mfma_f32_16x16x32_bf16; f32 stores.
// Block = 4 waves side-by-side in N; wave tile = 64(M) x 64(N); K = 128 (4 k-steps).
__global__ __launch_bounds__(256)
void lm_kernel(const unsigned short* __restrict__ xf,
               const unsigned short* __restrict__ wlm,
               float* __restrict__ out)
{
    const int lane = threadIdx.x & 63;
    const int wid  = threadIdx.x >> 6;
    const int nl   = lane & 15;
    const int quad = lane >> 4;
    const int t0 = blockIdx.x * 64;                 // M: 64 m-tiles of 64 -> 4096
    const int v0 = blockIdx.y * 256 + wid * 64;     // N: 197 n-tiles of 256

    bf16x8 a[4][4];
    const unsigned short* abase = xf + (size_t)(t0 + nl) * CC + quad * 8;
#pragma unroll
    for (int mi = 0; mi < 4; mi++)
#pragma unroll
        for (int ks = 0; ks < 4; ks++)
            a[mi][ks] = *reinterpret_cast<const bf16x8*>(abase + (size_t)mi * 16 * CC + ks * 32);

    f32x4 acc[4][4];
#pragma unroll
    for (int mi = 0; mi < 4; mi++)
#pragma unroll
        for (int ni = 0; ni < 4; ni++)
            acc[mi][ni] = (f32x4){0.f, 0.f, 0.f, 0.f};

#pragma unroll
    for (int ni = 0; ni < 4; ni++) {
        const int vr = v0 + ni * 16 + nl;
        const int vrc = vr < VV ? vr : VV - 1;      // clamp (stores are masked)
        const unsigned short* bbase = wlm + (size_t)vrc * CC + quad * 8;
        bf16x8 b[4];
#pragma unroll
        for (int ks = 0; ks < 4; ks++)
            b[ks] = *reinterpret_cast<const bf16x8*>(bbase + ks * 32);
#pragma unroll
        for (int mi = 0; mi < 4; mi++)
#pragma unroll
            for (int ks = 0; ks < 4; ks++)
                acc[mi][ni] = __builtin_amdgcn_mfma_f32_16x16x32_bf16(a[mi][ks], b[ks],
                                                                      acc[mi][ni], 0, 0, 0);
    }

#pragma unroll
    for (int ni = 0; ni < 4; ni++) {
        const int col = v0 + ni * 16 + nl;
        if (col < VV) {
#pragma unroll
            for (int mi = 0; mi < 4; mi++) {
                const size_t rowb = (size_t)(t0 + mi * 16 + quad * 4) * VV + col;
#pragma unroll
                for (int r = 0; r < 4; r++)
                    out[rowb + (size_t)r * VV] = acc[mi][ni][r];
            }
        }
    }
}

extern "C" void kernel_launch(void* const* d_in, const int* in_sizes, int n_in,
                              void* d_out, int out_size, void* d_ws, size_t ws_size,
                              hipStream_t stream)
{
    const int*   ids    = (const int*)d_in[0];
    const float* emb    = (const float*)d_in[1];
    const float* router = (const float*)d_in[2];
    const float* k_ex   = (const float*)d_in[3];
    const float* v_ex   = (const float*)d_in[4];
    const float* st_k   = (const float*)d_in[5];
    const float* st_v   = (const float*)d_in[6];
    const float* kvg    = (const float*)d_in[7];
    const float* Wq     = (const float*)d_in[8];
    const float* Wo     = (const float*)d_in[9];
    const float* Wmlp   = (const float*)d_in[10];
    const float* bmlp   = (const float*)d_in[11];
    const float* g1     = (const float*)d_in[12];
    const float* b1     = (const float*)d_in[13];
    const float* g2     = (const float*)d_in[14];
    const float* b2v    = (const float*)d_in[15];
    const float* wlm    = (const float*)d_in[16];

    float* out      = (float*)d_out;
    float* gate_out = out + (size_t)BT * VV;              // logits first, then gate_logits

    unsigned short* xfbuf = (unsigned short*)d_ws;        // 4096*128 bf16 = 1 MB
    unsigned short* wlmb  = xfbuf + (size_t)BT * CC;      // 50257*128 bf16 = 12.9 MB

    token_kernel<<<dim3(BT), dim3(128), 0, stream>>>(
        ids, emb, router, k_ex, v_ex, st_k, st_v, kvg,
        Wq, Wo, Wmlp, bmlp, g1, b1, g2, b2v, gate_out, xfbuf);

    const int n8 = (VV * CC) / 8;                         // 804112, exact
    convert_kernel<<<dim3((n8 + 255) / 256), dim3(256), 0, stream>>>(wlm, wlmb, n8);

    lm_kernel<<<dim3(64, 197), dim3(256), 0, stream>>>(xfbuf, wlmb, out);
}